// Round 1
// baseline (189.387 us; speedup 1.0000x reference)
//
#include <hip/hip_runtime.h>
#include <cstdint>
#include <cstddef>

// ---------------------------------------------------------------------------
// Zoner: out = softmax( mask ? -inf : tanh(zone@Wz+bz) . tanh(mean(txt)@Wt+bt) / sqrt(768) )
// B=32 L=80 Z=4096 D=768 DO=256.  Dominant cost: 402MB zone read + 51.5GFLOP GEMM.
// Strategy: bf16 MFMA fused GEMM (memory-bound, ~64us HBM floor).
// ---------------------------------------------------------------------------

typedef float  f32x4  __attribute__((ext_vector_type(4)));
typedef __bf16 bf16x4 __attribute__((ext_vector_type(4)));
typedef __bf16 bf16x8 __attribute__((ext_vector_type(8)));

// workspace layout (bytes)
#define OFF_T     0         // t[32][256] fp32          (32 KB)
#define OFF_WZT   32768     // WzT bf16 [256][768]      (384 KB)
#define OFF_FLAG  425984    // mask-format flag (int)
#define OFF_MP    426240    // mean partials [32][8][768] fp32 (768 KB)

__device__ __forceinline__ float fast_tanh(float x) {
    x = fminf(15.f, fmaxf(-15.f, x));
    float e2 = __expf(2.f * x);
    return (e2 - 1.f) * __builtin_amdgcn_rcpf(e2 + 1.f);
}

// ---------------------------------------------------------------------------
// prep1: blocks 0..255   : txt mean partial sums (b = blk>>3, 10 L-slices each)
//        blocks 256..319 : WzT[o][d] = bf16(Wz[d][o])
//        block  320      : mask dtype detector -> flag {0:int32,1:bytes,2:fp32,3:int64}
// ---------------------------------------------------------------------------
__global__ void prep1_kernel(const float* __restrict__ txt,
                             const float* __restrict__ Wz,
                             const void*  __restrict__ mask,
                             float* __restrict__ mp,
                             unsigned short* __restrict__ wzt,
                             int* __restrict__ flagp)
{
    const int blk = blockIdx.x, tid = threadIdx.x;
    if (blk < 256) {
        const int b = blk >> 3, part = blk & 7;
        const float* base = txt + (size_t)(b * 80 + part * 10) * 768;
        for (int d = tid; d < 768; d += 256) {
            float s = 0.f;
            #pragma unroll
            for (int l = 0; l < 10; ++l) s += base[l * 768 + d];
            mp[(b * 8 + part) * 768 + d] = s;
        }
    } else if (blk < 320) {
        const int i0 = (blk - 256) * 3072;
        for (int it = 0; it < 12; ++it) {
            int idx = i0 + it * 256 + tid;          // idx = o*768 + d
            int o = idx / 768;
            int d = idx - o * 768;
            __bf16 h = (__bf16)Wz[d * 256 + o];
            wzt[idx] = __builtin_bit_cast(unsigned short, h);
        }
    } else {
        // scan first 131072 bytes (valid for every candidate dtype)
        const unsigned* mw = (const unsigned*)mask;
        unsigned f_isf = 0, f_gt = 0, f_onz = 0, f_nz = 0;
        for (int i = tid; i < 32768; i += 256) {
            unsigned w = mw[i];
            if (w == 0x3F800000u) f_isf = 1;   // float 1.0 pattern
            else if (w > 1u)      f_gt  = 1;   // packed bool bytes
            if (w) { f_nz = 1; if (i & 1) f_onz = 1; }
        }
        __shared__ unsigned r[4];
        if (tid < 4) r[tid] = 0;
        __syncthreads();
        if (f_isf) atomicOr(&r[0], 1u);
        if (f_gt)  atomicOr(&r[1], 1u);
        if (f_onz) atomicOr(&r[2], 1u);
        if (f_nz)  atomicOr(&r[3], 1u);
        __syncthreads();
        if (tid == 0) {
            int flag;
            if (r[0])        flag = 2;   // fp32 0/1
            else if (r[1])   flag = 1;   // bytes
            else if (!r[3])  flag = 1;   // all-zero: byte path is always safe
            else if (!r[2])  flag = 3;   // nonzeros but all odd words zero -> int64
            else             flag = 0;   // int32
            *flagp = flag;
        }
    }
}

// ---------------------------------------------------------------------------
// prep2: mean = sum(partials)/80 ; t[b][o] = tanh(mean @ Wt + bt)   (fp32)
// ---------------------------------------------------------------------------
__global__ void prep2_kernel(const float* __restrict__ mp,
                             const float* __restrict__ Wt,
                             const float* __restrict__ bt,
                             float* __restrict__ tws)
{
    const int b = blockIdx.x, tid = threadIdx.x;
    __shared__ float meanv[768];
    for (int d = tid; d < 768; d += 256) {
        float s = 0.f;
        #pragma unroll
        for (int p = 0; p < 8; ++p) s += mp[(b * 8 + p) * 768 + d];
        meanv[d] = s * 0.0125f;   // 1/80
    }
    __syncthreads();
    float acc = bt[tid];
    for (int d = 0; d < 768; ++d) acc = fmaf(meanv[d], Wt[d * 256 + tid], acc);
    tws[b * 256 + tid] = tanhf(acc);
}

// ---------------------------------------------------------------------------
// Fused GEMM: logits[m] = sum_n tanh( (zone@Wz)[m,n] + bz[n] ) * t[b(m),n] / sqrt(768)
// BM=128 rows/block, N=256, K=768 (12 steps of BK=64), 8 waves (4 row-groups x 2 N-halves).
// A: fp32->bf16 reg-staged into XOR-swizzled LDS; B: global_load_lds from pre-swizzled src.
// LDS: A0[16K] A1[16K] B0[32K] B1[32K] = 96 KB, double-buffered.
// ---------------------------------------------------------------------------
__global__ __launch_bounds__(512, 2)
void gemm_kernel(const float* __restrict__ zone,
                 const unsigned short* __restrict__ wzt,   // WzT bf16 [256][768]
                 const float* __restrict__ tws,
                 const float* __restrict__ bz,
                 float* __restrict__ out)
{
    __shared__ alignas(16) unsigned char smem[98304];
    const int tid  = threadIdx.x;
    const int blk  = blockIdx.x;
    const int rowbase = blk << 7;          // 128 rows per block
    const int b    = rowbase >> 12;        // batch (4096 rows each)
    const int lane = tid & 63;
    const int wv   = tid >> 6;             // wave 0..7
    const int wr   = wv >> 1;              // row group 0..3 (32 rows each)
    const int wn   = wv & 1;               // N half 0..1 (128 cols each)
    const int l15  = lane & 15;
    const int l4   = lane >> 4;

    // MFMA fragment LDS addresses (rows of 128B, XOR-swizzled in 16B chunks by row&7)
    const int swz = (l15 & 7) << 4;
    const int kb0 = (l4 * 16) ^ swz;             // k-chunk 0 (k 0..31)
    const int kb1 = (64 + l4 * 16) ^ swz;        // k-chunk 1 (k 32..63)
    const int arow0  = (wr * 32 + l15) * 128;    // A rt=0 row byte offset
    const int arow1  = arow0 + 16 * 128;         // A rt=1
    const int bnbase = (wn * 128 + l15) * 128;   // B n byte offset (+ nt*2048)

    // A staging indices: iter i handles row (i*32 + tid>>4), float4 chunk (tid&15)
    const int sg_r  = tid >> 4;                  // 0..31
    const int sg_c4 = tid & 15;
    const int sg_kb = (sg_c4 * 8) ^ ((sg_r & 7) << 4);   // (i*32)%8==0 -> same for all i

    // B staging (global_load_lds, pre-swizzled source): iter i -> segment wv*4+i (1KB)
    const int b_n0  = wv * 32 + (lane >> 3);             // n for i=0; +8 per i
    const int b_csw = ((lane & 7) ^ (lane >> 3)) * 8;    // swizzled 16B-chunk, in bf16 elems

    f32x4 acc[2][8];
    #pragma unroll
    for (int i = 0; i < 2; ++i)
        #pragma unroll
        for (int j = 0; j < 8; ++j)
            acc[i][j] = f32x4{0.f, 0.f, 0.f, 0.f};

    const float* Ag = zone + (size_t)rowbase * 768;

    auto stage_b = [&](int kt, int buf) {
        #pragma unroll
        for (int i = 0; i < 4; ++i) {
            const unsigned short* gp = wzt + (size_t)((b_n0 + i * 8) * 768 + kt * 64 + b_csw);
            __builtin_amdgcn_global_load_lds(
                (const __attribute__((address_space(1))) void*)gp,
                (__attribute__((address_space(3))) void*)(smem + 32768 + buf * 32768 + (wv * 4 + i) * 1024),
                16, 0, 0);
        }
    };

    // ---- prologue: stage k-tile 0 into buffer 0 ----
    {
        stage_b(0, 0);
        f32x4 va[4];
        #pragma unroll
        for (int i = 0; i < 4; ++i)
            va[i] = *(const f32x4*)(Ag + (i * 32 + sg_r) * 768 + sg_c4 * 4);
        #pragma unroll
        for (int i = 0; i < 4; ++i) {
            bf16x4 h = { (__bf16)va[i][0], (__bf16)va[i][1], (__bf16)va[i][2], (__bf16)va[i][3] };
            *(bf16x4*)(smem + (i * 32 + sg_r) * 128 + sg_kb) = h;
        }
    }
    __syncthreads();

    // ---- main K loop ----
    for (int kt = 0; kt < 12; ++kt) {
        const int cur = kt & 1;
        const bool more = (kt < 11);
        f32x4 va[4];
        if (more) {
            const float* Agk = Ag + (kt + 1) * 64;
            #pragma unroll
            for (int i = 0; i < 4; ++i)
                va[i] = *(const f32x4*)(Agk + (i * 32 + sg_r) * 768 + sg_c4 * 4);
            stage_b(kt + 1, cur ^ 1);
        }
        // compute current tile
        {
            const unsigned aoff = cur * 16384u;
            const unsigned boff = 32768u + cur * 32768u;
            bf16x8 a00 = *(const bf16x8*)(smem + aoff + arow0 + kb0);
            bf16x8 a01 = *(const bf16x8*)(smem + aoff + arow0 + kb1);
            bf16x8 a10 = *(const bf16x8*)(smem + aoff + arow1 + kb0);
            bf16x8 a11 = *(const bf16x8*)(smem + aoff + arow1 + kb1);
            #pragma unroll
            for (int nt = 0; nt < 8; ++nt) {
                bf16x8 b0 = *(const bf16x8*)(smem + boff + bnbase + nt * 2048 + kb0);
                bf16x8 b1 = *(const bf16x8*)(smem + boff + bnbase + nt * 2048 + kb1);
                acc[0][nt] = __builtin_amdgcn_mfma_f32_16x16x32_bf16(a00, b0, acc[0][nt], 0, 0, 0);
                acc[0][nt] = __builtin_amdgcn_mfma_f32_16x16x32_bf16(a01, b1, acc[0][nt], 0, 0, 0);
                acc[1][nt] = __builtin_amdgcn_mfma_f32_16x16x32_bf16(a10, b0, acc[1][nt], 0, 0, 0);
                acc[1][nt] = __builtin_amdgcn_mfma_f32_16x16x32_bf16(a11, b1, acc[1][nt], 0, 0, 0);
            }
        }
        if (more) {
            const unsigned anext = (cur ^ 1) * 16384u;
            #pragma unroll
            for (int i = 0; i < 4; ++i) {
                bf16x4 h = { (__bf16)va[i][0], (__bf16)va[i][1], (__bf16)va[i][2], (__bf16)va[i][3] };
                *(bf16x4*)(smem + anext + (i * 32 + sg_r) * 128 + sg_kb) = h;
            }
        }
        __syncthreads();
    }

    // ---- epilogue: tanh(+bz) . t , reduce over N ----
    // C/D layout (verified m89/m91): col = lane&15, row = (lane>>4)*4 + reg
    const float* tb = tws + (b << 8);
    float tv[8], bzv[8];
    #pragma unroll
    for (int nt = 0; nt < 8; ++nt) {
        const int col = wn * 128 + nt * 16 + l15;
        tv[nt]  = tb[col];
        bzv[nt] = bz[col];
    }
    float p[2][4] = { {0.f,0.f,0.f,0.f}, {0.f,0.f,0.f,0.f} };
    #pragma unroll
    for (int rt = 0; rt < 2; ++rt)
        #pragma unroll
        for (int nt = 0; nt < 8; ++nt)
            #pragma unroll
            for (int r = 0; r < 4; ++r)
                p[rt][r] += fast_tanh(acc[rt][nt][r] + bzv[nt]) * tv[nt];

    #pragma unroll
    for (int rt = 0; rt < 2; ++rt)
        #pragma unroll
        for (int r = 0; r < 4; ++r) {
            float v = p[rt][r];
            v += __shfl_xor(v, 1);
            v += __shfl_xor(v, 2);
            v += __shfl_xor(v, 4);
            v += __shfl_xor(v, 8);
            p[rt][r] = v;
        }
    float* psum = (float*)smem;   // reuse A0 region; safe after final barrier
    if (l15 == 0) {
        #pragma unroll
        for (int rt = 0; rt < 2; ++rt)
            #pragma unroll
            for (int r = 0; r < 4; ++r) {
                const int rowl = wr * 32 + rt * 16 + l4 * 4 + r;
                psum[rowl * 2 + wn] = p[rt][r];
            }
    }
    __syncthreads();
    if (tid < 128) {
        const float s = psum[tid * 2] + psum[tid * 2 + 1];
        out[rowbase + tid] = s * 0.03608439182435161f;   // 1/sqrt(768)
    }
}

// ---------------------------------------------------------------------------
// softmax (in-place over d_out), one block per batch; mask applied per flag
// ---------------------------------------------------------------------------
__global__ void softmax_kernel(float* __restrict__ out,
                               const void* __restrict__ mask,
                               const int* __restrict__ flagp)
{
    const int b = blockIdx.x, tid = threadIdx.x;
    __shared__ float vals[4096];
    __shared__ float red[8];
    const int flag = *flagp;
    const int base = b << 12;
    float* po = out + base;
    float mx = -INFINITY;
    #pragma unroll
    for (int i = 0; i < 16; ++i) {
        const int z = i * 256 + tid;
        const int gi = base + z;
        bool msk;
        if (flag == 1)      msk = ((const unsigned char*)mask)[gi] != 0;
        else if (flag == 0) msk = ((const int*)mask)[gi] != 0;
        else if (flag == 2) msk = ((const float*)mask)[gi] != 0.f;
        else                msk = ((const long long*)mask)[gi] != 0;
        const float v = msk ? -INFINITY : po[z];
        vals[z] = v;
        mx = fmaxf(mx, v);
    }
    #pragma unroll
    for (int off = 32; off > 0; off >>= 1) mx = fmaxf(mx, __shfl_xor(mx, off));
    if ((tid & 63) == 0) red[tid >> 6] = mx;
    __syncthreads();
    mx = fmaxf(fmaxf(red[0], red[1]), fmaxf(red[2], red[3]));
    float s = 0.f;
    #pragma unroll
    for (int i = 0; i < 16; ++i) {
        const int z = i * 256 + tid;
        const float e = __expf(vals[z] - mx);   // -inf -> 0
        vals[z] = e;
        s += e;
    }
    #pragma unroll
    for (int off = 32; off > 0; off >>= 1) s += __shfl_xor(s, off);
    if ((tid & 63) == 0) red[4 + (tid >> 6)] = s;
    __syncthreads();
    const float inv = 1.f / (red[4] + red[5] + red[6] + red[7]);
    #pragma unroll
    for (int i = 0; i < 16; ++i) {
        const int z = i * 256 + tid;
        po[z] = vals[z] * inv;
    }
}

// ---------------------------------------------------------------------------
extern "C" void kernel_launch(void* const* d_in, const int* in_sizes, int n_in,
                              void* d_out, int out_size, void* d_ws, size_t ws_size,
                              hipStream_t stream)
{
    (void)in_sizes; (void)n_in; (void)out_size; (void)ws_size;
    const float* txt  = (const float*)d_in[0];
    const float* zone = (const float*)d_in[1];
    const void*  mask = d_in[2];
    const float* Wt   = (const float*)d_in[3];
    const float* bt   = (const float*)d_in[4];
    const float* Wz   = (const float*)d_in[5];
    const float* bz   = (const float*)d_in[6];
    float* out = (float*)d_out;
    char*  ws  = (char*)d_ws;
    float* tws           = (float*)(ws + OFF_T);
    unsigned short* wzt  = (unsigned short*)(ws + OFF_WZT);
    int*   flagp         = (int*)(ws + OFF_FLAG);
    float* mp            = (float*)(ws + OFF_MP);

    prep1_kernel<<<321, 256, 0, stream>>>(txt, Wz, mask, mp, wzt, flagp);
    prep2_kernel<<<32, 256, 0, stream>>>(mp, Wt, bt, tws);
    gemm_kernel<<<1024, 512, 0, stream>>>(zone, wzt, tws, bz, out);
    softmax_kernel<<<32, 256, 0, stream>>>(out, mask, flagp);
}

// Round 3
// 152.709 us; speedup vs baseline: 1.2402x; 1.2402x over previous
//
#include <hip/hip_runtime.h>
#include <cstdint>
#include <cstddef>

// ---------------------------------------------------------------------------
// Zoner: out = softmax( mask ? -inf : tanh(zone@Wz+bz) . tanh(mean(txt)@Wt+bt) / sqrt(768) )
// B=32 L=80 Z=4096 D=768 DO=256.  Dominant cost: 402MB zone read (HBM floor ~64us).
// R1: counted-vmcnt pipeline (T3/T4); raw s_barrier; 2-deep A reg prefetch.
// R2: fix prologue register-rotation parity (va[cur] must hold A(kt+1) at
//     iter-kt entry; R1 staged A(0) twice -> k-block 1 used wrong A tile).
// ---------------------------------------------------------------------------

typedef float  f32x4  __attribute__((ext_vector_type(4)));
typedef __bf16 bf16x4 __attribute__((ext_vector_type(4)));
typedef __bf16 bf16x8 __attribute__((ext_vector_type(8)));

// workspace layout (bytes)
#define OFF_T     0         // t[32][256] fp32          (32 KB)
#define OFF_WZT   32768     // WzT bf16 [256][768]      (384 KB)
#define OFF_FLAG  425984    // mask-format flag (int)
#define OFF_MP    426240    // mean partials [32][8][768] fp32 (768 KB)

__device__ __forceinline__ float fast_tanh(float x) {
    x = fminf(15.f, fmaxf(-15.f, x));
    float e2 = __expf(2.f * x);
    return (e2 - 1.f) * __builtin_amdgcn_rcpf(e2 + 1.f);
}

// ---------------------------------------------------------------------------
// prep1: blocks 0..255   : txt mean partial sums (b = blk>>3, 10 L-slices each)
//        blocks 256..319 : WzT[o][d] = bf16(Wz[d][o])
//        block  320      : mask dtype detector -> flag {0:int32,1:bytes,2:fp32,3:int64}
// ---------------------------------------------------------------------------
__global__ void prep1_kernel(const float* __restrict__ txt,
                             const float* __restrict__ Wz,
                             const void*  __restrict__ mask,
                             float* __restrict__ mp,
                             unsigned short* __restrict__ wzt,
                             int* __restrict__ flagp)
{
    const int blk = blockIdx.x, tid = threadIdx.x;
    if (blk < 256) {
        const int b = blk >> 3, part = blk & 7;
        const float* base = txt + (size_t)(b * 80 + part * 10) * 768;
        for (int d = tid; d < 768; d += 256) {
            float s = 0.f;
            #pragma unroll
            for (int l = 0; l < 10; ++l) s += base[l * 768 + d];
            mp[(b * 8 + part) * 768 + d] = s;
        }
    } else if (blk < 320) {
        const int i0 = (blk - 256) * 3072;
        for (int it = 0; it < 12; ++it) {
            int idx = i0 + it * 256 + tid;          // idx = o*768 + d
            int o = idx / 768;
            int d = idx - o * 768;
            __bf16 h = (__bf16)Wz[d * 256 + o];
            wzt[idx] = __builtin_bit_cast(unsigned short, h);
        }
    } else {
        // scan first 32768 bytes (valid window for every candidate dtype)
        const unsigned* mw = (const unsigned*)mask;
        unsigned f_isf = 0, f_gt = 0, f_onz = 0, f_nz = 0;
        for (int i = tid; i < 8192; i += 256) {
            unsigned w = mw[i];
            if (w == 0x3F800000u) f_isf = 1;   // float 1.0 pattern
            else if (w > 1u)      f_gt  = 1;   // packed bool bytes
            if (w) { f_nz = 1; if (i & 1) f_onz = 1; }
        }
        __shared__ unsigned r[4];
        if (tid < 4) r[tid] = 0;
        __syncthreads();
        if (f_isf) atomicOr(&r[0], 1u);
        if (f_gt)  atomicOr(&r[1], 1u);
        if (f_onz) atomicOr(&r[2], 1u);
        if (f_nz)  atomicOr(&r[3], 1u);
        __syncthreads();
        if (tid == 0) {
            int flag;
            if (r[0])        flag = 2;   // fp32 0/1
            else if (r[1])   flag = 1;   // bytes
            else if (!r[3])  flag = 1;   // all-zero: byte path is always safe
            else if (!r[2])  flag = 3;   // nonzeros but all odd words zero -> int64
            else             flag = 0;   // int32
            *flagp = flag;
        }
    }
}

// ---------------------------------------------------------------------------
// prep2: mean = sum(partials)/80 ; t[b][o] = tanh(mean @ Wt + bt)   (fp32)
// ---------------------------------------------------------------------------
__global__ void prep2_kernel(const float* __restrict__ mp,
                             const float* __restrict__ Wt,
                             const float* __restrict__ bt,
                             float* __restrict__ tws)
{
    const int b = blockIdx.x, tid = threadIdx.x;
    __shared__ float meanv[768];
    for (int d = tid; d < 768; d += 256) {
        float s = 0.f;
        #pragma unroll
        for (int p = 0; p < 8; ++p) s += mp[(b * 8 + p) * 768 + d];
        meanv[d] = s * 0.0125f;   // 1/80
    }
    __syncthreads();
    float acc = bt[tid];
    for (int d = 0; d < 768; ++d) acc = fmaf(meanv[d], Wt[d * 256 + tid], acc);
    tws[b * 256 + tid] = tanhf(acc);
}

// ---------------------------------------------------------------------------
// Fused GEMM: logits[m] = sum_n tanh( (zone@Wz)[m,n] + bz[n] ) * t[b(m),n] / sqrt(768)
// BM=128 rows/block, N=256, K=768 (12 steps of BK=64), 8 waves (4 row-groups x 2 N-halves).
// Pipeline invariant: at iter-kt entry, va[cur] holds A(kt+1) (in flight).
//   stage_b(kt+1) first (oldest in VMEM queue), then load_a(kt+2, va[cur^1]);
//   write_a(cur^1, va[cur]) -> compiler waits vmcnt(8) (A(kt+1) done);
//   asm vmcnt(4) -> B(kt+1) done, A(kt+2) stays in flight across s_barrier.
// LDS: A0[16K] A1[16K] B0[32K] B1[32K] = 96 KB.
// ---------------------------------------------------------------------------
__global__ __launch_bounds__(512, 2)
void gemm_kernel(const float* __restrict__ zone,
                 const unsigned short* __restrict__ wzt,   // WzT bf16 [256][768]
                 const float* __restrict__ tws,
                 const float* __restrict__ bz,
                 float* __restrict__ out)
{
    __shared__ alignas(16) unsigned char smem[98304];
    const int tid  = threadIdx.x;
    const int blk  = blockIdx.x;
    const int rowbase = blk << 7;          // 128 rows per block
    const int b    = rowbase >> 12;        // batch (4096 rows each)
    const int lane = tid & 63;
    const int wv   = tid >> 6;             // wave 0..7
    const int wr   = wv >> 1;              // row group 0..3 (32 rows each)
    const int wn   = wv & 1;               // N half 0..1 (128 cols each)
    const int l15  = lane & 15;
    const int l4   = lane >> 4;

    // MFMA fragment LDS addresses (rows of 128B, XOR-swizzled in 16B chunks by row&7)
    const int swz = (l15 & 7) << 4;
    const int kb0 = (l4 * 16) ^ swz;             // k-chunk 0 (k 0..31)
    const int kb1 = (64 + l4 * 16) ^ swz;        // k-chunk 1 (k 32..63)
    const int arow0  = (wr * 32 + l15) * 128;    // A rt=0 row byte offset
    const int arow1  = arow0 + 16 * 128;         // A rt=1
    const int bnbase = (wn * 128 + l15) * 128;   // B n byte offset (+ nt*2048)

    // A staging indices: iter i handles row (i*32 + tid>>4), float4 chunk (tid&15)
    const int sg_r  = tid >> 4;                  // 0..31
    const int sg_c4 = tid & 15;
    const int sg_kb = (sg_c4 * 8) ^ ((sg_r & 7) << 4);

    // B staging (global_load_lds, pre-swizzled source): iter i -> segment wv*4+i (1KB)
    const int b_n0  = wv * 32 + (lane >> 3);             // n for i=0; +8 per i
    const int b_csw = ((lane & 7) ^ (lane >> 3)) * 8;    // swizzled 16B-chunk, in bf16 elems

    f32x4 acc[2][8];
    #pragma unroll
    for (int i = 0; i < 2; ++i)
        #pragma unroll
        for (int j = 0; j < 8; ++j)
            acc[i][j] = f32x4{0.f, 0.f, 0.f, 0.f};

    const float* Ag = zone + (size_t)rowbase * 768;

    auto stage_b = [&](int kt, int buf) {
        #pragma unroll
        for (int i = 0; i < 4; ++i) {
            const unsigned short* gp = wzt + (size_t)((b_n0 + i * 8) * 768 + kt * 64 + b_csw);
            __builtin_amdgcn_global_load_lds(
                (const __attribute__((address_space(1))) void*)gp,
                (__attribute__((address_space(3))) void*)(smem + 32768 + buf * 32768 + (wv * 4 + i) * 1024),
                16, 0, 0);
        }
    };
    auto load_a = [&](int kt, f32x4* va) {
        const float* Agk = Ag + kt * 64;
        #pragma unroll
        for (int i = 0; i < 4; ++i)
            va[i] = *(const f32x4*)(Agk + (i * 32 + sg_r) * 768 + sg_c4 * 4);
    };
    auto write_a = [&](int buf, const f32x4* va) {
        #pragma unroll
        for (int i = 0; i < 4; ++i) {
            bf16x4 h = { (__bf16)va[i][0], (__bf16)va[i][1], (__bf16)va[i][2], (__bf16)va[i][3] };
            *(bf16x4*)(smem + buf * 16384 + (i * 32 + sg_r) * 128 + sg_kb) = h;
        }
    };

    // ---- prologue ----
    // va[1] is the A(0) temp (lifetime ends here); va[0] takes A(1) so that
    // at kt=0 (cur=0) the invariant va[cur]==A(kt+1) holds.
    f32x4 va[2][4];
    stage_b(0, 0);
    __builtin_amdgcn_sched_barrier(0);
    load_a(0, va[1]);
    write_a(0, va[1]);            // compiler drains vmcnt for va[1] (B(0) retires too)
    load_a(1, va[0]);             // A(1) in flight across the barrier
    asm volatile("s_waitcnt vmcnt(4) lgkmcnt(0)" ::: "memory");  // B(0)+A(0) done, A(1) flying
    __builtin_amdgcn_s_barrier();
    __builtin_amdgcn_sched_barrier(0);

    // ---- main K loop (fully unrolled; va[] statically indexed) ----
    #pragma unroll
    for (int kt = 0; kt < 12; ++kt) {
        const int cur = kt & 1;
        if (kt < 11) {
            stage_b(kt + 1, cur ^ 1);            // B(kt+1): oldest in queue
            __builtin_amdgcn_sched_barrier(0);   // pin glds before A-loads
        }
        if (kt < 10)
            load_a(kt + 2, va[cur ^ 1]);         // A(kt+2): newest in queue
        // compute current tile
        {
            const unsigned aoff = cur * 16384u;
            const unsigned boff = 32768u + cur * 32768u;
            bf16x8 a00 = *(const bf16x8*)(smem + aoff + arow0 + kb0);
            bf16x8 a01 = *(const bf16x8*)(smem + aoff + arow0 + kb1);
            bf16x8 a10 = *(const bf16x8*)(smem + aoff + arow1 + kb0);
            bf16x8 a11 = *(const bf16x8*)(smem + aoff + arow1 + kb1);
            #pragma unroll
            for (int nt = 0; nt < 8; ++nt) {
                bf16x8 b0 = *(const bf16x8*)(smem + boff + bnbase + nt * 2048 + kb0);
                bf16x8 b1 = *(const bf16x8*)(smem + boff + bnbase + nt * 2048 + kb1);
                acc[0][nt] = __builtin_amdgcn_mfma_f32_16x16x32_bf16(a00, b0, acc[0][nt], 0, 0, 0);
                acc[0][nt] = __builtin_amdgcn_mfma_f32_16x16x32_bf16(a01, b1, acc[0][nt], 0, 0, 0);
                acc[1][nt] = __builtin_amdgcn_mfma_f32_16x16x32_bf16(a10, b0, acc[1][nt], 0, 0, 0);
                acc[1][nt] = __builtin_amdgcn_mfma_f32_16x16x32_bf16(a11, b1, acc[1][nt], 0, 0, 0);
            }
        }
        if (kt < 11)
            write_a(cur ^ 1, va[cur]);           // A(kt+1) -> buf cur^1; compiler waits vmcnt(8)
        if (kt < 10)
            asm volatile("s_waitcnt vmcnt(4) lgkmcnt(0)" ::: "memory");   // B(kt+1) done, A(kt+2) flying
        else if (kt == 10)
            asm volatile("s_waitcnt vmcnt(0) lgkmcnt(0)" ::: "memory");   // drain tail
        else
            asm volatile("s_waitcnt lgkmcnt(0)" ::: "memory");
        __builtin_amdgcn_s_barrier();
        __builtin_amdgcn_sched_barrier(0);
    }

    // ---- epilogue: tanh(+bz) . t , reduce over N ----
    // C/D layout (verified m89/m91): col = lane&15, row = (lane>>4)*4 + reg
    const float* tb = tws + (b << 8);
    float tv[8], bzv[8];
    #pragma unroll
    for (int nt = 0; nt < 8; ++nt) {
        const int col = wn * 128 + nt * 16 + l15;
        tv[nt]  = tb[col];
        bzv[nt] = bz[col];
    }
    float p[2][4] = { {0.f,0.f,0.f,0.f}, {0.f,0.f,0.f,0.f} };
    #pragma unroll
    for (int rt = 0; rt < 2; ++rt)
        #pragma unroll
        for (int nt = 0; nt < 8; ++nt)
            #pragma unroll
            for (int r = 0; r < 4; ++r)
                p[rt][r] += fast_tanh(acc[rt][nt][r] + bzv[nt]) * tv[nt];

    #pragma unroll
    for (int rt = 0; rt < 2; ++rt)
        #pragma unroll
        for (int r = 0; r < 4; ++r) {
            float v = p[rt][r];
            v += __shfl_xor(v, 1);
            v += __shfl_xor(v, 2);
            v += __shfl_xor(v, 4);
            v += __shfl_xor(v, 8);
            p[rt][r] = v;
        }
    float* psum = (float*)smem;   // reuse A0 region; safe after final barrier
    if (l15 == 0) {
        #pragma unroll
        for (int rt = 0; rt < 2; ++rt)
            #pragma unroll
            for (int r = 0; r < 4; ++r) {
                const int rowl = wr * 32 + rt * 16 + l4 * 4 + r;
                psum[rowl * 2 + wn] = p[rt][r];
            }
    }
    __syncthreads();
    if (tid < 128) {
        const float s = psum[tid * 2] + psum[tid * 2 + 1];
        out[rowbase + tid] = s * 0.03608439182435161f;   // 1/sqrt(768)
    }
}

// ---------------------------------------------------------------------------
// softmax (in-place over d_out), one block per batch; mask applied per flag
// ---------------------------------------------------------------------------
__global__ void softmax_kernel(float* __restrict__ out,
                               const void* __restrict__ mask,
                               const int* __restrict__ flagp)
{
    const int b = blockIdx.x, tid = threadIdx.x;
    __shared__ float vals[4096];
    __shared__ float red[8];
    const int flag = *flagp;
    const int base = b << 12;
    float* po = out + base;
    float mx = -INFINITY;
    #pragma unroll
    for (int i = 0; i < 16; ++i) {
        const int z = i * 256 + tid;
        const int gi = base + z;
        bool msk;
        if (flag == 1)      msk = ((const unsigned char*)mask)[gi] != 0;
        else if (flag == 0) msk = ((const int*)mask)[gi] != 0;
        else if (flag == 2) msk = ((const float*)mask)[gi] != 0.f;
        else                msk = ((const long long*)mask)[gi] != 0;
        const float v = msk ? -INFINITY : po[z];
        vals[z] = v;
        mx = fmaxf(mx, v);
    }
    #pragma unroll
    for (int off = 32; off > 0; off >>= 1) mx = fmaxf(mx, __shfl_xor(mx, off));
    if ((tid & 63) == 0) red[tid >> 6] = mx;
    __syncthreads();
    mx = fmaxf(fmaxf(red[0], red[1]), fmaxf(red[2], red[3]));
    float s = 0.f;
    #pragma unroll
    for (int i = 0; i < 16; ++i) {
        const int z = i * 256 + tid;
        const float e = __expf(vals[z] - mx);   // -inf -> 0
        vals[z] = e;
        s += e;
    }
    #pragma unroll
    for (int off = 32; off > 0; off >>= 1) s += __shfl_xor(s, off);
    if ((tid & 63) == 0) red[4 + (tid >> 6)] = s;
    __syncthreads();
    const float inv = 1.f / (red[4] + red[5] + red[6] + red[7]);
    #pragma unroll
    for (int i = 0; i < 16; ++i) {
        const int z = i * 256 + tid;
        po[z] = vals[z] * inv;
    }
}

// ---------------------------------------------------------------------------
extern "C" void kernel_launch(void* const* d_in, const int* in_sizes, int n_in,
                              void* d_out, int out_size, void* d_ws, size_t ws_size,
                              hipStream_t stream)
{
    (void)in_sizes; (void)n_in; (void)out_size; (void)ws_size;
    const float* txt  = (const float*)d_in[0];
    const float* zone = (const float*)d_in[1];
    const void*  mask = d_in[2];
    const float* Wt   = (const float*)d_in[3];
    const float* bt   = (const float*)d_in[4];
    const float* Wz   = (const float*)d_in[5];
    const float* bz   = (const float*)d_in[6];
    float* out = (float*)d_out;
    char*  ws  = (char*)d_ws;
    float* tws           = (float*)(ws + OFF_T);
    unsigned short* wzt  = (unsigned short*)(ws + OFF_WZT);
    int*   flagp         = (int*)(ws + OFF_FLAG);
    float* mp            = (float*)(ws + OFF_MP);

    prep1_kernel<<<321, 256, 0, stream>>>(txt, Wz, mask, mp, wzt, flagp);
    prep2_kernel<<<32, 256, 0, stream>>>(mp, Wt, bt, tws);
    gemm_kernel<<<1024, 512, 0, stream>>>(zone, wzt, tws, bz, out);
    softmax_kernel<<<32, 256, 0, stream>>>(out, mask, flagp);
}